// Round 2
// baseline (689.991 us; speedup 1.0000x reference)
//
#include <hip/hip_runtime.h>

// data (262144, 512) fp32, latentZ (1,512) fp32, mu (1,) fp32, tau (1,) fp32.
// Outputs: ir_mu (262144,) then ir_tau (262144,), concatenated flat fp32.
#define ROWS 262144
#define LATENT 512
#define TPB 256
#define BLOCKS 2048
#define TOTAL_WAVES (BLOCKS * (TPB / 64))   // 8192 waves, 8 per SIMD at launch
#define ROWS_PER_WAVE (ROWS / TOTAL_WAVES)  // 32
#define RPI 4                               // rows per iteration
#define ITERS (ROWS_PER_WAVE / RPI)         // 8

// Clang native vector type.
typedef float vf4 __attribute__((ext_vector_type(4)));

// Persistent waves, 4 rows per iteration:
//  - 8 vf4 loads (8 KB/wave) in flight; any compiler-inserted vmcnt drain is
//    amortized over 4 rows instead of 2.
//  - PLAIN (cached) loads: nontemporal removed. Zero reuse means cache policy
//    can't help algorithmically, and nt is the prime suspect for the observed
//    ~1.65 TB/s (26% of achievable) streaming rate.
//  - 8 independent butterfly chains (s0..3, q0..3) interleave on the DS pipe.
__global__ __launch_bounds__(TPB) void linear_svi_kernel(
    const float* __restrict__ data,
    const float* __restrict__ latentZ,
    const float* __restrict__ mu_p,
    const float* __restrict__ tau_p,
    float* __restrict__ out) {
  const int lane = threadIdx.x & 63;
  const int wave_g = (blockIdx.x << 2) + (threadIdx.x >> 6);  // 0..8191

  const float mu = mu_p[0];
  const float tau = tau_p[0];

  // latentZ fragment: row-invariant, loaded once, L1/L2-resident.
  const vf4* zv = (const vf4*)latentZ;
  const vf4 z0 = zv[lane];
  const vf4 z1 = zv[64 + lane];

  // Rows this iteration: base_row + j*8192, j=0..3.
  int base_row = wave_g;

  vf4 x[RPI][2], nx[RPI][2];
#pragma unroll
  for (int j = 0; j < RPI; ++j) {
    const vf4* p =
        (const vf4*)(data + (size_t)(wave_g + j * TOTAL_WAVES) * LATENT);
    x[j][0] = p[lane];
    x[j][1] = p[64 + lane];
  }

  for (int it = 0; it < ITERS; ++it) {
    // Prefetch next group of 4 rows before touching current dependents.
    const int nbase = base_row + RPI * TOTAL_WAVES;
    if (it + 1 < ITERS) {
#pragma unroll
      for (int j = 0; j < RPI; ++j) {
        const vf4* p =
            (const vf4*)(data + (size_t)(nbase + j * TOTAL_WAVES) * LATENT);
        nx[j][0] = p[lane];
        nx[j][1] = p[64 + lane];
      }
    }

    float s0, s1, s2, s3, q0, q1, q2, q3;
    {
      float pr, dd;
#define ROWACC(ss, qq, J)                                     \
      ss = 0.0f; qq = 0.0f;                                   \
      pr = z0.x * x[J][0].x; ss += pr; dd = pr - mu; qq = fmaf(dd, dd, qq); \
      pr = z0.y * x[J][0].y; ss += pr; dd = pr - mu; qq = fmaf(dd, dd, qq); \
      pr = z0.z * x[J][0].z; ss += pr; dd = pr - mu; qq = fmaf(dd, dd, qq); \
      pr = z0.w * x[J][0].w; ss += pr; dd = pr - mu; qq = fmaf(dd, dd, qq); \
      pr = z1.x * x[J][1].x; ss += pr; dd = pr - mu; qq = fmaf(dd, dd, qq); \
      pr = z1.y * x[J][1].y; ss += pr; dd = pr - mu; qq = fmaf(dd, dd, qq); \
      pr = z1.z * x[J][1].z; ss += pr; dd = pr - mu; qq = fmaf(dd, dd, qq); \
      pr = z1.w * x[J][1].w; ss += pr; dd = pr - mu; qq = fmaf(dd, dd, qq);
      ROWACC(s0, q0, 0)
      ROWACC(s1, q1, 1)
      ROWACC(s2, q2, 2)
      ROWACC(s3, q3, 3)
#undef ROWACC
    }

    // 64-lane butterfly; 8 independent chains interleave on the DS pipe.
#pragma unroll
    for (int off = 32; off > 0; off >>= 1) {
      s0 += __shfl_xor(s0, off, 64);
      s1 += __shfl_xor(s1, off, 64);
      s2 += __shfl_xor(s2, off, 64);
      s3 += __shfl_xor(s3, off, 64);
      q0 += __shfl_xor(q0, off, 64);
      q1 += __shfl_xor(q1, off, 64);
      q2 += __shfl_xor(q2, off, 64);
      q3 += __shfl_xor(q3, off, 64);
    }

    // All lanes hold all 8 totals. Lanes 0..7 store {mu,tau} x 4 rows.
    // Constant-index selects only (runtime-indexed arrays would spill, #20).
    if (lane < 2 * RPI) {
      const int j = lane >> 1;  // which row
      float sv = s0, qv = q0;
      sv = (j == 1) ? s1 : sv;  qv = (j == 1) ? q1 : qv;
      sv = (j == 2) ? s2 : sv;  qv = (j == 2) ? q2 : qv;
      sv = (j == 3) ? s3 : sv;  qv = (j == 3) ? q3 : qv;
      const int r = base_row + j * TOTAL_WAVES;
      const float ir_mu = (sv + mu) * (1.0f / 513.0f);
      const float dm = ir_mu - mu;
      const float ir_tau = (tau + 256.0f) / (1.0f + 0.5f * qv + dm * dm);
      const float v = (lane & 1) ? ir_tau : ir_mu;
      out[(size_t)(lane & 1) * ROWS + r] = v;
    }

#pragma unroll
    for (int j = 0; j < RPI; ++j) {
      x[j][0] = nx[j][0];
      x[j][1] = nx[j][1];
    }
    base_row = nbase;
  }
}

extern "C" void kernel_launch(void* const* d_in, const int* in_sizes, int n_in,
                              void* d_out, int out_size, void* d_ws, size_t ws_size,
                              hipStream_t stream) {
  const float* data    = (const float*)d_in[0];
  const float* latentZ = (const float*)d_in[1];
  const float* mu      = (const float*)d_in[2];
  const float* tau     = (const float*)d_in[3];
  float* out = (float*)d_out;

  linear_svi_kernel<<<dim3(BLOCKS), dim3(TPB), 0, stream>>>(data, latentZ, mu,
                                                            tau, out);
}